// Round 7
// baseline (529.290 us; speedup 1.0000x reference)
//
#include <hip/hip_runtime.h>
#include <hip/hip_bf16.h>
#include <math.h>

#define NN 1024
#define PP 256
#define INC 1024

typedef _Float16 f16_t;
typedef __attribute__((ext_vector_type(8))) _Float16 f16x8;
typedef __attribute__((ext_vector_type(4))) _Float16 f16x4;
typedef __attribute__((ext_vector_type(4))) float f32x4;
typedef __attribute__((ext_vector_type(16))) float f32x16;
typedef __attribute__((ext_vector_type(4))) int i32x4;

__device__ __forceinline__ float gelu_exact(float v) {
    return 0.5f * v * (1.0f + erff(v * 0.70710678118654752440f));
}

__device__ __forceinline__ void cvt_store(const float* __restrict__ s,
                                          f16_t* __restrict__ d, int j) {
    float4 v = ((const float4*)s)[j];
    f16x4 o = {(f16_t)v.x, (f16_t)v.y, (f16_t)v.z, (f16_t)v.w};
    ((f16x4*)d)[j] = o;
}

// One kernel: all weight casts + pos table + bias concat.
__global__ __launch_bounds__(256) void prep_k(
    const float* __restrict__ w_ds, const float* __restrict__ wq,
    const float* __restrict__ wk, const float* __restrict__ wv,
    const float* __restrict__ w1, const float* __restrict__ rel_h,
    const float* __restrict__ rel_w, const float* __restrict__ bq,
    const float* __restrict__ bk, const float* __restrict__ bv,
    f16_t* __restrict__ wdsh, f16_t* __restrict__ wqkv,
    f16_t* __restrict__ w1h, f16_t* __restrict__ post,
    float* __restrict__ bqkv)
{
    int i = blockIdx.x * 256 + threadIdx.x;
    if (i < 65536) {
        cvt_store(w_ds, wdsh, i);
    } else if (i < 81920) {
        cvt_store(wq, wqkv, i - 65536);
    } else if (i < 98304) {
        cvt_store(wk, wqkv + 65536, i - 81920);
    } else if (i < 114688) {
        cvt_store(wv, wqkv + 131072, i - 98304);
    } else if (i < 180224) {
        cvt_store(w1, w1h, i - 114688);
    } else if (i < 245760) {
        int j = i - 180224;
        int flat = j * 4;
        int d = flat & 63;
        int n = (flat >> 6) & 1023;
        int h = flat >> 16;
        f16x4 pk;
        #pragma unroll
        for (int jj = 0; jj < 4; ++jj) {
            float v = rel_h[(h * 64 + d + jj) * 32 + (n & 31)]
                    + rel_w[(h * 64 + d + jj) * 32 + (n >> 5)];
            pk[jj] = (f16_t)v;
        }
        *(f16x4*)&post[flat] = pk;
    } else if (i < 245952) {
        int j = i - 245760;
        int which = j >> 6, r = j & 63;
        const float* src = which == 0 ? bq : (which == 1 ? bk : bv);
        float4 v = ((const float4*)src)[r];
        ((float4*)bqkv)[which * 64 + r] = v;
    }
}

// x [B][C=1024][N=1024] f32  ->  xt [B][N][C] f16  (vectorized both sides)
__global__ __launch_bounds__(256) void transpose_xk(const float* __restrict__ x,
                                                    f16_t* __restrict__ xt) {
    __shared__ float T[64][68];
    int tid = threadIdx.x;
    int n0 = blockIdx.x * 64, c0 = blockIdx.y * 64;
    size_t b = blockIdx.z;
    const float* xp = x + b * 1048576;
    int cl = tid >> 4, n4 = (tid & 15) * 4;
    #pragma unroll
    for (int it = 0; it < 4; ++it) {
        float4 v = *(const float4*)&xp[(size_t)(c0 + cl + it * 16) * 1024 + n0 + n4];
        *(float4*)&T[cl + it * 16][n4] = v;
    }
    __syncthreads();
    int nl = tid >> 3, ck = tid & 7;
    f16_t* xo = xt + b * 1048576;
    #pragma unroll
    for (int it = 0; it < 2; ++it) {
        int n = nl + it * 32;
        f16x8 pk;
        #pragma unroll
        for (int j = 0; j < 8; ++j) pk[j] = (f16_t)T[ck * 8 + j][n];
        *(f16x8*)&xo[(size_t)(n0 + n) * 1024 + c0 + ck * 8] = pk;
    }
}

// MFMA GEMM, ONE WAVE per block: (MFR*16)m x 32n per wave.
// C[b][m][n] = sum_k A[m][k] * Bt[b][n][k] (+bias[m]).
// mode 0: Cq[(b*N+n)*M+m] f16. mode 1: merged qkv (M=768). mode 3: gelu+resid f32.
template<int MFR>
__global__ __launch_bounds__(64) void hgemm(
    const f16_t* __restrict__ A, const f16_t* __restrict__ Bt,
    const float* __restrict__ bias, const float* __restrict__ resid,
    f16_t* __restrict__ Cq, f16_t* __restrict__ Ck, f16_t* __restrict__ Cv,
    float* __restrict__ Cf,
    int M, int N, int K, int mode)
{
    int l = threadIdx.x;
    int lo = l & 15, hi = l >> 4;
    int m0 = blockIdx.y * (MFR * 16);
    int n0 = blockIdx.x * 32;
    size_t bb = blockIdx.z;

    const f16_t* Ap = A + (size_t)(m0 + lo) * K + hi * 8;
    const f16_t* Bq = Bt + bb * (size_t)N * K + (size_t)(n0 + lo) * K + hi * 8;

    f32x4 acc[MFR][2] = {};

    #pragma unroll 2
    for (int k0 = 0; k0 < K; k0 += 32) {
        f16x8 bfr0 = *(const f16x8*)(Bq + k0);
        f16x8 bfr1 = *(const f16x8*)(Bq + (size_t)16 * K + k0);
        #pragma unroll
        for (int fm = 0; fm < MFR; ++fm) {
            f16x8 af = *(const f16x8*)(Ap + (size_t)fm * 16 * K + k0);
            acc[fm][0] = __builtin_amdgcn_mfma_f32_16x16x32_f16(af, bfr0, acc[fm][0], 0, 0, 0);
            acc[fm][1] = __builtin_amdgcn_mfma_f32_16x16x32_f16(af, bfr1, acc[fm][1], 0, 0, 0);
        }
    }

    #pragma unroll
    for (int fn = 0; fn < 2; ++fn) {
        int n = n0 + fn * 16 + lo;
        #pragma unroll
        for (int fm = 0; fm < MFR; ++fm) {
            int mb = m0 + fm * 16 + hi * 4;
            f32x4 a = acc[fm][fn];
            if (mode == 0) {
                f16x4 st;
                #pragma unroll
                for (int r = 0; r < 4; ++r) st[r] = (f16_t)a[r];
                *(f16x4*)&Cq[((size_t)bb * N + n) * M + mb] = st;
            } else if (mode == 1) {
                int which = mb >> 8;
                int mloc = mb & 255;
                int hh = mloc >> 6, d0 = mloc & 63;
                if (which == 2) {
                    #pragma unroll
                    for (int r = 0; r < 4; ++r)
                        Cv[(((size_t)bb * 4 + hh) * 64 + d0 + r) * NN + n] = (f16_t)(a[r] + bias[mb + r]);
                } else {
                    f16_t* dst = which ? Ck : Cq;
                    f16x4 st;
                    #pragma unroll
                    for (int r = 0; r < 4; ++r) st[r] = (f16_t)(a[r] + bias[mb + r]);
                    *(f16x4*)&dst[(((size_t)bb * 4 + hh) * NN + n) * 64 + d0] = st;
                }
            } else {
                #pragma unroll
                for (int r = 0; r < 4; ++r) {
                    size_t idx = ((size_t)bb * M + mb + r) * N + n;
                    Cf[idx] = gelu_exact(a[r]) + resid[idx];
                }
            }
        }
    }
}

// Swapped-operand 32x32 MFMA flash attention, 4 waves/block (in-block split-j).
// Wave w handles j in [w*256, w*256+256) for the block's 32 q-rows; LDS combine at end.
// q_t,k_t: [B*H][N][64]. v_b: [B*H][64][N]. pos_t: [H][N][64]. o: [B][N][256] f16.
__global__ __launch_bounds__(256, 4) void attn_mfma(
    const f16_t* __restrict__ q_t, const f16_t* __restrict__ k_t,
    const f16_t* __restrict__ v_b, const f16_t* __restrict__ pos_t,
    f16_t* __restrict__ o)
{
    __shared__ float cm[4][32], cl[4][32];
    __shared__ __align__(16) float cacc[2][32][68];
    int tid = threadIdx.x;
    int wvi = tid >> 6;                 // j-split index 0..3
    int l = tid & 63;
    int lq = l & 31;
    int half = l >> 5;
    int h = blockIdx.y, b = blockIdx.z;
    int q0 = blockIdx.x * 32;
    size_t base = (size_t)(b * 4 + h) * (NN * 64);

    // B-frags (hoisted): cols q = lq; k-chunks: 0-3 = q(d), 4-7 = pos(d)
    f16x8 Bq0, Bq1, Bq2, Bq3, Bq4, Bq5, Bq6, Bq7;
    {
        const f16_t* qr = q_t + base + (size_t)(q0 + lq) * 64 + half * 8;
        Bq0 = *(const f16x8*)(qr);
        Bq1 = *(const f16x8*)(qr + 16);
        Bq2 = *(const f16x8*)(qr + 32);
        Bq3 = *(const f16x8*)(qr + 48);
        const f16_t* pr = pos_t + ((size_t)h * NN + q0 + lq) * 64 + half * 8;
        Bq4 = *(const f16x8*)(pr);
        Bq5 = *(const f16x8*)(pr + 16);
        Bq6 = *(const f16x8*)(pr + 32);
        Bq7 = *(const f16x8*)(pr + 48);
    }

    f32x16 accD0 = {}, accD1 = {};   // O^T d-blocks 0-31 / 32-63, col q = lq
    float m_run = -1e30f, l_run = 0.0f;

    const f16_t* kbase = k_t + base + ((size_t)wvi * 256 + lq) * 64 + half * 8;
    const f16_t* qabase = q_t + base + ((size_t)wvi * 256 + lq) * 64 + half * 8;
    const f16_t* vbase = v_b + base + (size_t)lq * NN + wvi * 256 + half * 8;

    f16x8 aK0, aK1, aK2, aK3, aQ0, aQ1, aQ2, aQ3, aV00, aV01, aV10, aV11;
    f16x8 bK0, bK1, bK2, bK3, bQ0, bQ1, bQ2, bQ3, bV00, bV01, bV10, bV11;

#define LOADT(S, J) do { \
    const f16_t* ka_ = kbase + (size_t)(J) * 64; \
    S##K0 = *(const f16x8*)(ka_);       S##K1 = *(const f16x8*)(ka_ + 16); \
    S##K2 = *(const f16x8*)(ka_ + 32);  S##K3 = *(const f16x8*)(ka_ + 48); \
    const f16_t* qa_ = qabase + (size_t)(J) * 64; \
    S##Q0 = *(const f16x8*)(qa_);       S##Q1 = *(const f16x8*)(qa_ + 16); \
    S##Q2 = *(const f16x8*)(qa_ + 32);  S##Q3 = *(const f16x8*)(qa_ + 48); \
    const f16_t* va_ = vbase + (J); \
    S##V00 = *(const f16x8*)(va_);          S##V01 = *(const f16x8*)(va_ + 16); \
    S##V10 = *(const f16x8*)(va_ + 32 * NN); S##V11 = *(const f16x8*)(va_ + 32 * NN + 16); \
} while (0)

#define COMPUTE(S) do { \
    f32x16 sc = {}; \
    sc = __builtin_amdgcn_mfma_f32_32x32x16_f16(S##K0, Bq0, sc, 0, 0, 0); \
    sc = __builtin_amdgcn_mfma_f32_32x32x16_f16(S##K1, Bq1, sc, 0, 0, 0); \
    sc = __builtin_amdgcn_mfma_f32_32x32x16_f16(S##K2, Bq2, sc, 0, 0, 0); \
    sc = __builtin_amdgcn_mfma_f32_32x32x16_f16(S##K3, Bq3, sc, 0, 0, 0); \
    sc = __builtin_amdgcn_mfma_f32_32x32x16_f16(S##Q0, Bq4, sc, 0, 0, 0); \
    sc = __builtin_amdgcn_mfma_f32_32x32x16_f16(S##Q1, Bq5, sc, 0, 0, 0); \
    sc = __builtin_amdgcn_mfma_f32_32x32x16_f16(S##Q2, Bq6, sc, 0, 0, 0); \
    sc = __builtin_amdgcn_mfma_f32_32x32x16_f16(S##Q3, Bq7, sc, 0, 0, 0); \
    float mt = sc[0]; \
    _Pragma("unroll") \
    for (int r = 1; r < 16; ++r) mt = fmaxf(mt, sc[r]); \
    mt = fmaxf(mt, __shfl_xor(mt, 32, 64)); \
    if (!__all(mt <= m_run + 8.0f)) { \
        float mnew = fmaxf(m_run, mt); \
        float alpha = __expf(m_run - mnew); \
        m_run = mnew; l_run *= alpha; \
        _Pragma("unroll") \
        for (int r = 0; r < 16; ++r) { accD0[r] *= alpha; accD1[r] *= alpha; } \
    } \
    float p[16]; float rs = 0.0f; \
    _Pragma("unroll") \
    for (int r = 0; r < 16; ++r) { p[r] = __expf(sc[r] - m_run); rs += p[r]; } \
    rs += __shfl_xor(rs, 32, 64); \
    l_run += rs; \
    int w0 = __builtin_bit_cast(int, __builtin_amdgcn_cvt_pkrtz(p[0], p[1])); \
    int w1 = __builtin_bit_cast(int, __builtin_amdgcn_cvt_pkrtz(p[2], p[3])); \
    int w2 = __builtin_bit_cast(int, __builtin_amdgcn_cvt_pkrtz(p[4], p[5])); \
    int w3 = __builtin_bit_cast(int, __builtin_amdgcn_cvt_pkrtz(p[6], p[7])); \
    int w4 = __builtin_bit_cast(int, __builtin_amdgcn_cvt_pkrtz(p[8], p[9])); \
    int w5 = __builtin_bit_cast(int, __builtin_amdgcn_cvt_pkrtz(p[10], p[11])); \
    int w6 = __builtin_bit_cast(int, __builtin_amdgcn_cvt_pkrtz(p[12], p[13])); \
    int w7 = __builtin_bit_cast(int, __builtin_amdgcn_cvt_pkrtz(p[14], p[15])); \
    int x0 = __shfl_xor(w0, 32, 64), x1 = __shfl_xor(w1, 32, 64); \
    int x2 = __shfl_xor(w2, 32, 64), x3 = __shfl_xor(w3, 32, 64); \
    int x4 = __shfl_xor(w4, 32, 64), x5 = __shfl_xor(w5, 32, 64); \
    int x6 = __shfl_xor(w6, 32, 64), x7 = __shfl_xor(w7, 32, 64); \
    i32x4 pb0 = { half ? x2 : w0, half ? x3 : w1, half ? w2 : x0, half ? w3 : x1 }; \
    i32x4 pb1 = { half ? x6 : w4, half ? x7 : w5, half ? w6 : x4, half ? w7 : x5 }; \
    f16x8 Pf0 = __builtin_bit_cast(f16x8, pb0); \
    f16x8 Pf1 = __builtin_bit_cast(f16x8, pb1); \
    accD0 = __builtin_amdgcn_mfma_f32_32x32x16_f16(S##V00, Pf0, accD0, 0, 0, 0); \
    accD0 = __builtin_amdgcn_mfma_f32_32x32x16_f16(S##V01, Pf1, accD0, 0, 0, 0); \
    accD1 = __builtin_amdgcn_mfma_f32_32x32x16_f16(S##V10, Pf0, accD1, 0, 0, 0); \
    accD1 = __builtin_amdgcn_mfma_f32_32x32x16_f16(S##V11, Pf1, accD1, 0, 0, 0); \
} while (0)

    // 8 tiles per wave, depth-1 prefetch
    LOADT(a, 0);
    for (int t = 0; t < 8; t += 2) {
        LOADT(b, (t + 1) * 32);
        COMPUTE(a);
        LOADT(a, ((t + 2) & 7) * 32);
        COMPUTE(b);
    }
#undef LOADT
#undef COMPUTE

    // ---- cross-wave combine ----
    if (half == 0) { cm[wvi][lq] = m_run; cl[wvi][lq] = l_run; }
    __syncthreads();
    float m0v = cm[0][lq], m1v = cm[1][lq], m2v = cm[2][lq], m3v = cm[3][lq];
    float mg = fmaxf(fmaxf(m0v, m1v), fmaxf(m2v, m3v));
    float lg = cl[0][lq] * __expf(m0v - mg) + cl[1][lq] * __expf(m1v - mg)
             + cl[2][lq] * __expf(m2v - mg) + cl[3][lq] * __expf(m3v - mg);
    float alpha = __expf(m_run - mg);
    #pragma unroll
    for (int r = 0; r < 16; ++r) { accD0[r] *= alpha; accD1[r] *= alpha; }

    // waves 1,3 publish
    if (wvi & 1) {
        int bi = wvi >> 1;
        #pragma unroll
        for (int rg = 0; rg < 4; ++rg) {
            int d0 = rg * 8 + half * 4;
            float4 v0 = {accD0[rg*4+0], accD0[rg*4+1], accD0[rg*4+2], accD0[rg*4+3]};
            float4 v1 = {accD1[rg*4+0], accD1[rg*4+1], accD1[rg*4+2], accD1[rg*4+3]};
            *(float4*)&cacc[bi][lq][d0] = v0;
            *(float4*)&cacc[bi][lq][32 + d0] = v1;
        }
    }
    __syncthreads();
    // waves 0,2 absorb; wave 2 republishes
    if (!(wvi & 1)) {
        int bi = wvi >> 1;
        #pragma unroll
        for (int rg = 0; rg < 4; ++rg) {
            int d0 = rg * 8 + half * 4;
            float4 v0 = *(const float4*)&cacc[bi][lq][d0];
            float4 v1 = *(const float4*)&cacc[bi][lq][32 + d0];
            accD0[rg*4+0] += v0.x; accD0[rg*4+1] += v0.y; accD0[rg*4+2] += v0.z; accD0[rg*4+3] += v0.w;
            accD1[rg*4+0] += v1.x; accD1[rg*4+1] += v1.y; accD1[rg*4+2] += v1.z; accD1[rg*4+3] += v1.w;
        }
    }
    __syncthreads();
    if (wvi == 2) {
        #pragma unroll
        for (int rg = 0; rg < 4; ++rg) {
            int d0 = rg * 8 + half * 4;
            float4 v0 = {accD0[rg*4+0], accD0[rg*4+1], accD0[rg*4+2], accD0[rg*4+3]};
            float4 v1 = {accD1[rg*4+0], accD1[rg*4+1], accD1[rg*4+2], accD1[rg*4+3]};
            *(float4*)&cacc[1][lq][d0] = v0;
            *(float4*)&cacc[1][lq][32 + d0] = v1;
        }
    }
    __syncthreads();
    if (wvi == 0) {
        #pragma unroll
        for (int rg = 0; rg < 4; ++rg) {
            int d0 = rg * 8 + half * 4;
            float4 v0 = *(const float4*)&cacc[1][lq][d0];
            float4 v1 = *(const float4*)&cacc[1][lq][32 + d0];
            accD0[rg*4+0] += v0.x; accD0[rg*4+1] += v0.y; accD0[rg*4+2] += v0.z; accD0[rg*4+3] += v0.w;
            accD1[rg*4+0] += v1.x; accD1[rg*4+1] += v1.y; accD1[rg*4+2] += v1.z; accD1[rg*4+3] += v1.w;
        }
        float inv = 1.0f / lg;
        size_t orow = ((size_t)b * NN + q0 + lq) * 256 + h * 64;
        #pragma unroll
        for (int rg = 0; rg < 4; ++rg) {
            f16x4 s0, s1;
            #pragma unroll
            for (int c = 0; c < 4; ++c) {
                s0[c] = (f16_t)(accD0[rg * 4 + c] * inv);
                s1[c] = (f16_t)(accD1[rg * 4 + c] * inv);
            }
            *(f16x4*)&o[orow + rg * 8 + half * 4] = s0;
            *(f16x4*)&o[orow + 32 + rg * 8 + half * 4] = s1;
        }
    }
}

// LayerNorm over P=256: o [B][N][256] f16 -> yt f16. One wave per row.
__global__ __launch_bounds__(256) void ln_k(const f16_t* __restrict__ o,
                                            f16_t* __restrict__ yt,
                                            const float* __restrict__ lw,
                                            const float* __restrict__ lb)
{
    int tid = threadIdx.x;
    int wv = tid >> 6, l = tid & 63;
    size_t row = (size_t)blockIdx.x * 4 + wv;
    f16x4 v4 = ((const f16x4*)(o + row * 256))[l];
    float v[4];
    #pragma unroll
    for (int j = 0; j < 4; ++j) v[j] = (float)v4[j];
    float s = v[0] + v[1] + v[2] + v[3];
    float q = v[0]*v[0] + v[1]*v[1] + v[2]*v[2] + v[3]*v[3];
    #pragma unroll
    for (int off = 1; off < 64; off <<= 1) {
        s += __shfl_xor(s, off, 64);
        q += __shfl_xor(q, off, 64);
    }
    float mean = s * (1.0f / 256.0f);
    float var = q * (1.0f / 256.0f) - mean * mean;
    float rstd = rsqrtf(var + 1e-6f);
    f32x4 w4 = ((const f32x4*)lw)[l];
    f32x4 b4 = ((const f32x4*)lb)[l];
    f16x4 o4;
    #pragma unroll
    for (int j = 0; j < 4; ++j)
        o4[j] = (f16_t)((v[j] - mean) * rstd * w4[j] + b4[j]);
    ((f16x4*)(yt + row * 256))[l] = o4;
}

extern "C" void kernel_launch(void* const* d_in, const int* in_sizes, int n_in,
                              void* d_out, int out_size, void* d_ws, size_t ws_size,
                              hipStream_t stream) {
    const float* x     = (const float*)d_in[0];
    const float* w_ds  = (const float*)d_in[1];
    const float* wq    = (const float*)d_in[2];
    const float* bq    = (const float*)d_in[3];
    const float* wk    = (const float*)d_in[4];
    const float* bk    = (const float*)d_in[5];
    const float* wv    = (const float*)d_in[6];
    const float* bv    = (const float*)d_in[7];
    const float* rel_h = (const float*)d_in[8];
    const float* rel_w = (const float*)d_in[9];
    const float* ln_w  = (const float*)d_in[10];
    const float* ln_b  = (const float*)d_in[11];
    const float* w1    = (const float*)d_in[12];
    float* out = (float*)d_out;

    f16_t* xt    = (f16_t*)d_ws;             // [B][N][C]       32 MB
    f16_t* wdsh  = xt + 16777216;            // [256][1024]
    f16_t* wqkv  = wdsh + 262144;            // [768][256]
    f16_t* w1h   = wqkv + 196608;            // [1024][256]
    f16_t* post  = w1h + 262144;             // [4][1024][64]
    f16_t* out0t = post + 262144;            // [B][N][256]
    f16_t* qt    = out0t + 4194304;          // [B*4][N][64]
    f16_t* kt    = qt + 4194304;
    f16_t* vb    = kt + 4194304;             // [B*4][64][N]
    f16_t* ytb   = vb + 4194304;             // [B][N][256]
    f16_t* oat   = ytb + 4194304;            // [B][N][256]
    float* bqkv  = (float*)(oat + 4194304);  // [768]

    prep_k<<<961, 256, 0, stream>>>(w_ds, wq, wk, wv, w1, rel_h, rel_w,
                                    bq, bk, bv, wdsh, wqkv, w1h, post, bqkv);
    transpose_xk<<<dim3(16, 16, 16), 256, 0, stream>>>(x, xt);

    // out0_t[b][n][p] = w_ds * x   (32m x 32n waves -> 4096 waves)
    hgemm<2><<<dim3(32, 8, 16), 64, 0, stream>>>(wdsh, xt, nullptr, nullptr,
                                                 out0t, nullptr, nullptr, nullptr,
                                                 PP, NN, INC, 0);
    // q,k,v in one launch (M=768, 12288 waves)
    hgemm<2><<<dim3(32, 24, 16), 64, 0, stream>>>(wqkv, out0t, bqkv, nullptr,
                                                  qt, kt, vb, nullptr,
                                                  768, NN, PP, 1);
    // attention -> oat [b][n][256] f16  (4-wave blocks, split-j)
    attn_mfma<<<dim3(32, 4, 16), 256, 0, stream>>>(qt, kt, vb, post, oat);
    // layernorm -> ytb f16
    ln_k<<<4096, 256, 0, stream>>>(oat, ytb, ln_w, ln_b);
    // out = gelu(w1 * y) + x
    hgemm<4><<<dim3(32, 16, 16), 64, 0, stream>>>(w1h, ytb, nullptr, x,
                                                  nullptr, nullptr, nullptr, out,
                                                  INC, NN, PP, 3);
}